// Round 8
// baseline (46.409 us; speedup 1.0000x reference)
//
#include <hip/hip_runtime.h>

#define DW 512
#define DH 512
#define RROWS 8
#define BORDER (-2.0f)

typedef float v4f __attribute__((ext_vector_type(4)));

__device__ __forceinline__ float max3f(float a, float b, float c) {
    return fmaxf(fmaxf(a, b), c);
}

// Separable dilation, vertical-first. All 10 row-loads are issued upfront and
// PINNED before any consume via sched_barrier(0) — without it the compiler
// sinks the loads to ~4-deep (round-6 VGPR_Count=32 proved this), capping
// memory-level parallelism. Each lane owns 4 contiguous columns (16B/lane,
// 128 tx = full 512-wide row). Horizontal max via intra-wave shfl on the
// vertical-max registers; half-row boundary column (255/256) via a 1-lane
// exec-masked scalar load per row.
__global__ __launch_bounds__(256) void dilate3x3_kernel(
    const float* __restrict__ in, float* __restrict__ out) {
    const int tx   = threadIdx.x;              // 0..127
    const int lane = tx & 63;
    const int x0   = tx << 2;
    const int rowgrp = blockIdx.y * blockDim.y + threadIdx.y;
    const int y0   = rowgrp * RROWS;
    const int img  = blockIdx.z;

    const float* __restrict__ p = in  + (size_t)img * DH * DW;
    float*       __restrict__ q = out + (size_t)img * DH * DW;

    const bool needL = (lane == 0  && x0 == 256);       // right-half wave: col 255
    const bool needR = (lane == 63 && x0 + 4 == 256);   // left-half wave: col 256
    const bool needE = needL || needR;
    const int  ex    = needL ? 255 : 256;

    v4f   raw[RROWS + 2];
    float e[RROWS + 2];

    // Issue all row loads back-to-back (static indices, fully unrolled).
    #pragma unroll
    for (int i = 0; i < RROWS + 2; ++i) {
        const int y = y0 - 1 + i;
        if (y < 0 || y >= DH) {
            raw[i] = (v4f)BORDER;
            e[i]   = BORDER;
        } else {
            const float* row = p + (size_t)y * DW;
            raw[i] = *reinterpret_cast<const v4f*>(row + x0);
            e[i]   = needE ? row[ex] : BORDER;   // exec-masked: 1 lane/wave
        }
    }

    // Fence: forbid the scheduler from sinking any of the loads above past
    // this point — forces all 10 loads in flight before the first consume.
    __builtin_amdgcn_sched_barrier(0);

    #pragma unroll
    for (int r = 0; r < RROWS; ++r) {
        v4f vm;
        vm.x = max3f(raw[r].x, raw[r + 1].x, raw[r + 2].x);
        vm.y = max3f(raw[r].y, raw[r + 1].y, raw[r + 2].y);
        vm.z = max3f(raw[r].z, raw[r + 1].z, raw[r + 2].z);
        vm.w = max3f(raw[r].w, raw[r + 1].w, raw[r + 2].w);
        float em = max3f(e[r], e[r + 1], e[r + 2]);
        float ln = __shfl(vm.w, (lane + 63) & 63);
        float rn = __shfl(vm.x, (lane + 1) & 63);
        float left  = (lane == 0)  ? ((x0 == 0)      ? BORDER : em) : ln;
        float right = (lane == 63) ? ((x0 + 4 == DW) ? BORDER : em) : rn;
        v4f o;
        o.x = max3f(left, vm.x, vm.y);
        o.y = max3f(vm.x, vm.y, vm.z);
        o.z = max3f(vm.y, vm.z, vm.w);
        o.w = max3f(vm.z, vm.w, right);
        __builtin_nontemporal_store(o,
            reinterpret_cast<v4f*>(q + (size_t)(y0 + r) * DW + x0));
    }
}

extern "C" void kernel_launch(void* const* d_in, const int* in_sizes, int n_in,
                              void* d_out, int out_size, void* d_ws, size_t ws_size,
                              hipStream_t stream) {
    const float* img = (const float*)d_in[0];
    float* out = (float*)d_out;

    const int n_imgs = in_sizes[0] / (DH * DW);    // 16*8 = 128

    dim3 block(128, 2, 1);                         // 256 threads, 4 waves
    dim3 grid(1, DH / (RROWS * 2), n_imgs);        // (1, 32, 128)
    dilate3x3_kernel<<<grid, block, 0, stream>>>(img, out);
}